// Round 4
// baseline (251021.216 us; speedup 1.0000x reference)
//
#include <hip/hip_runtime.h>
#include <math.h>

#define NCH 2048
#define NT 256
#define NTP 512

typedef __attribute__((ext_vector_type(8))) short short8v;
typedef __attribute__((ext_vector_type(4))) float float4v;
typedef unsigned short ushortt;

// Static device scratch.
__device__ float2 g_X[(size_t)NCH * 128 * 65];
__device__ float2 g_Y[(size_t)NCH * 128 * 65];
__device__ float2 g_ring[(size_t)NCH * 57 * 132];
__device__ int    g_owner[64 * 33];

// Frag-swizzled split-bf16 basis matrices, fixed-size slot per res.
#define B1SLOT (8 * 16 * 64 * 8)
#define B2SLOT (4 * 8 * 64 * 8)
#define B3SLOT (4 * 16 * 64 * 8)
#define B4SLOT (8 * 8 * 64 * 8)
__device__ ushortt g_B1h[(size_t)57 * B1SLOT], g_B1l[(size_t)57 * B1SLOT];
__device__ ushortt g_B2h[(size_t)57 * B2SLOT], g_B2l[(size_t)57 * B2SLOT];
__device__ ushortt g_B3h[(size_t)57 * B3SLOT], g_B3l[(size_t)57 * B3SLOT];
__device__ ushortt g_B4h[(size_t)57 * B4SLOT], g_B4l[(size_t)57 * B4SLOT];

__device__ __forceinline__ float gelu_exact(float v) {
  return 0.5f * v * (1.0f + erff(v * 0.70710678118654752440f));
}
#define ROT(co, si, cs, ss) { float _n = co * cs - si * ss; si = si * cs + co * ss; co = _n; }

// fp32 -> (hi, lo) bf16 split, both rne.
__device__ __forceinline__ void bsplit(float x, ushortt& hh, ushortt& ll) {
  unsigned u = __float_as_uint(x);
  unsigned hb = (u + 0x7FFFu + ((u >> 16) & 1u)) >> 16;
  float hf = __uint_as_float(hb << 16);
  hh = (ushortt)hb;
  float lr = x - hf;
  unsigned ul = __float_as_uint(lr);
  unsigned lb = (ul + 0x7FFFu + ((ul >> 16) & 1u)) >> 16;
  ll = (ushortt)lb;
}

// ---------------------------------------------------------------------------
// R1 / R2: rfft2(x)/16384 into g_X (verified in rounds 1-3).
// ---------------------------------------------------------------------------
__global__ __launch_bounds__(NT) void r1_kernel(const float* __restrict__ x) {
  __shared__ float xb[16 * 128];
  __shared__ float tw[256];
  int ch = blockIdx.x >> 3, grp = blockIdx.x & 7;
  int tid = threadIdx.x;
  for (int t = tid; t < 128; t += NT) {
    float s, co; sincosf(6.283185307179586f * (float)t / 128.0f, &s, &co);
    tw[2 * t] = co; tw[2 * t + 1] = s;
  }
  const float* xp = x + ((size_t)ch * 128 + grp * 16) * 128;
  for (int i = tid; i < 16 * 128; i += NT) xb[i] = xp[i];
  __syncthreads();
  for (int idx = tid; idx < 16 * 65; idx += NT) {
    int u = idx / 65, k2 = idx - 65 * u;
    const float* row = xb + u * 128;
    float cb = tw[2 * k2], sbr = tw[2 * k2 + 1];
    int t2 = (2 * k2) & 127;
    float cs = tw[2 * t2], ss = tw[2 * t2 + 1];
    float ca = 1.f, sa = 0.f;
    float ar = 0.f, ai = 0.f;
    for (int v = 0; v < 128; v += 2) {
      float x0 = row[v], x1 = row[v + 1];
      ar += x0 * ca; ai -= x0 * sa;
      ar += x1 * cb; ai -= x1 * sbr;
      ROT(ca, sa, cs, ss); ROT(cb, sbr, cs, ss);
    }
    g_Y[((size_t)ch * 128 + grp * 16 + u) * 65 + k2] = make_float2(ar, ai);
  }
}

__global__ __launch_bounds__(NT) void r2_kernel() {
  __shared__ float2 yb[128 * 8];
  __shared__ float tw[256];
  int ch = blockIdx.x / 9, cg = blockIdx.x - 9 * ch;
  int c0 = cg * 8, nc = min(8, 65 - c0);
  int tid = threadIdx.x;
  for (int t = tid; t < 128; t += NT) {
    float s, co; sincosf(6.283185307179586f * (float)t / 128.0f, &s, &co);
    tw[2 * t] = co; tw[2 * t + 1] = s;
  }
  for (int i = tid; i < 128 * nc; i += NT) {
    int u = i / nc, j = i - nc * u;
    yb[u * 8 + j] = g_Y[((size_t)ch * 128 + u) * 65 + c0 + j];
  }
  __syncthreads();
  const float inv = 1.0f / 16384.0f;
  for (int idx = tid; idx < 64 * nc; idx += NT) {
    int k1 = idx & 63, j = idx >> 6;
    float cb = tw[2 * k1], sbr = tw[2 * k1 + 1];
    int t2 = (2 * k1) & 127;
    float cs = tw[2 * t2], ss = tw[2 * t2 + 1];
    float ca = 1.f, sa = 0.f;
    float ar = 0.f, ai = 0.f, br = 0.f, bi = 0.f;
    for (int u = 0; u < 128; u += 2) {
      float2 e = yb[u * 8 + j];
      float pr = e.x * ca + e.y * sa, pi = e.y * ca - e.x * sa;
      ar += pr; ai += pi; br += pr; bi += pi;
      e = yb[(u + 1) * 8 + j];
      float pr2 = e.x * cb + e.y * sbr, pi2 = e.y * cb - e.x * sbr;
      ar += pr2; ai += pi2; br -= pr2; bi -= pi2;
      ROT(ca, sa, cs, ss); ROT(cb, sbr, cs, ss);
    }
    g_X[((size_t)ch * 128 + k1) * 65 + c0 + j]      = make_float2(ar * inv, ai * inv);
    g_X[((size_t)ch * 128 + k1 + 64) * 65 + c0 + j] = make_float2(br * inv, bi * inv);
  }
}

// ---------------------------------------------------------------------------
// Owner map (verified).
// ---------------------------------------------------------------------------
__device__ __forceinline__ int owner_slot(int rr, int k2, int ri) {
  if (ri == 0) {
    if (k2 <= 4) {
      if (rr <= 3) return rr * 5 + k2;
      if (rr >= 60) return (rr - 56) * 5 + k2;
    }
    return -1;
  }
  int res = 16 + 2 * ri, c = res / 2, h = c / 2;
  if (c & 1) {
    if (rr == h && k2 <= h) return k2;
    if (rr == 64 - h && k2 <= h) return (h + 1) + k2;
    if (k2 == h) {
      if (rr <= h) return 2 * (h + 1) + rr;
      if (rr >= 64 - h) return 2 * (h + 1) + (rr - 64 + c);
    }
  } else {
    if (rr == 64 - h && k2 <= h) return (h + 1) + k2;
    if (k2 == h) {
      if (rr >= 64 - h) return 2 * (h + 1) + (rr - 64 + c);
      if (rr < h) return 2 * (h + 1) + rr;
    }
  }
  return -1;
}

__global__ __launch_bounds__(NT) void owner_kernel() {
  int cell = blockIdx.x * NT + threadIdx.x;
  if (cell >= 64 * 33) return;
  int rr = cell / 33, k2 = cell - 33 * (cell / 33);
  int result = -1;
  for (int ri = 56; ri >= 0 && result < 0; ri--) {
    int slot = owner_slot(rr, k2, ri);
    if (slot >= 0) result = ri * 256 + slot;
  }
  g_owner[cell] = result;
}

// ---------------------------------------------------------------------------
// Basis build: per res, 4 frag-swizzled split-bf16 matrices.
// Element (ka, nu) -> idx = ((kt*NtA + nt)*64 + lane)*8 + j,
// kt=ka>>5, q=(ka>>3)&3, j=ka&7, nt=nu>>4, lane=(q<<4)|(nu&15).
// ---------------------------------------------------------------------------
__device__ __forceinline__ void bput(ushortt* H, ushortt* L, int NtA, int ka, int nu, float v) {
  int kt = ka >> 5, q = (ka >> 3) & 3, j = ka & 7;
  int nt = nu >> 4;
  int lanei = (q << 4) | (nu & 15);
  size_t idx = (((size_t)(kt * NtA + nt)) * 64 + lanei) * 8 + j;
  ushortt hh, ll; bsplit(v, hh, ll);
  H[idx] = hh; L[idx] = ll;
}

__global__ __launch_bounds__(256) void basis_kernel() {
  int ri = blockIdx.x;
  int r = 16 + 2 * ri;
  int c = r >> 1, cp1 = c + 1, h = c >> 1;
  int rp = (c + 1) >> 1, rn = c >> 1;
  int jp = ((cp1 + 15) >> 4) << 4;
  int tid = threadIdx.x;
  __shared__ float zr[128], zi[128], yr[128], yi[128];
  for (int d = tid; d < r; d += 256) {
    float sr = 0.f, si = 0.f;
    for (int qq = 0; qq < c; qq++) {
      int f = (qq < rp) ? qq : (r - rn + (qq - rp));
      int t = (f * d) % r;
      float ss, cc; sincosf(6.283185307179586f * (float)t / (float)r, &ss, &cc);
      sr += cc; si += ss;
    }
    zr[d] = sr; zi[d] = si;
    float ar = 1.f, ai = 0.f;
    for (int k = 1; k <= h; k++) {
      int t = (k * d) % r;
      float ss, cc; sincosf(6.283185307179586f * (float)t / (float)r, &ss, &cc);
      ar += 2.f * cc; ai += 2.f * ss;
    }
    float inv = 1.f / ((float)r * (float)r);
    yr[d] = ar * inv; yi[d] = ai * inv;
  }
  ushortt* b1h = g_B1h + (size_t)ri * B1SLOT; ushortt* b1l = g_B1l + (size_t)ri * B1SLOT;
  ushortt* b2h = g_B2h + (size_t)ri * B2SLOT; ushortt* b2l = g_B2l + (size_t)ri * B2SLOT;
  ushortt* b3h = g_B3h + (size_t)ri * B3SLOT; ushortt* b3l = g_B3l + (size_t)ri * B3SLOT;
  ushortt* b4h = g_B4h + (size_t)ri * B4SLOT; ushortt* b4l = g_B4l + (size_t)ri * B4SLOT;
  for (int e = tid; e < B1SLOT; e += 256) { b1h[e] = 0; b1l[e] = 0; }
  for (int e = tid; e < B2SLOT; e += 256) { b2h[e] = 0; b2l[e] = 0; }
  for (int e = tid; e < B3SLOT; e += 256) { b3h[e] = 0; b3l[e] = 0; }
  for (int e = tid; e < B4SLOT; e += 256) { b4h[e] = 0; b4l[e] = 0; }
  __syncthreads();
  if (r < 128) {
    // B1: inverse column DFT, complex as stacked real. ka=(s*r+k1), nu=2u+s'.
    for (int idx = tid; idx < 2 * r * 2 * r; idx += 256) {
      int ka = idx / (2 * r), nu = idx - (idx / (2 * r)) * 2 * r;
      int s = ka >= r, k1 = ka - (s ? r : 0);
      int sp = nu & 1, u = nu >> 1;
      int t = (u * k1) % r;
      float ss, cc; sincosf(6.283185307179586f * (float)t / (float)r, &ss, &cc);
      float v = (s == 0) ? (sp == 0 ? cc : ss) : (sp == 0 ? -ss : cc);
      bput(b1h, b1l, 16, ka, nu, v);
    }
    // B2: Hermitian row synthesis. ka=s*jp+j (j<=c), nu=v.
    for (int idx = tid; idx < 2 * cp1 * r; idx += 256) {
      int sj = idx / r, v = idx - (idx / r) * r;
      int s = sj >= cp1, j = sj - (s ? cp1 : 0);
      int t = (v * j) % r;
      float ss, cc; sincosf(6.283185307179586f * (float)t / (float)r, &ss, &cc);
      float w = (j == 0 || j == c) ? 1.f : 2.f;
      float val = (s == 0) ? w * cc : -w * ss;
      bput(b2h, b2l, 8, s * jp + j, v, val);
    }
  }
  // B3: smooth col operator Y~ (circulant). ka=v2, nu=2*v2'+p.
  for (int idx = tid; idx < r * 2 * r; idx += 256) {
    int v2 = idx / (2 * r), nu = idx - (idx / (2 * r)) * 2 * r;
    int p = nu & 1, v2p = nu >> 1;
    int d = (v2p - v2 + r) % r;
    bput(b3h, b3l, 16, v2, nu, p ? yi[d] : yr[d]);
  }
  // B4: smooth row operator Z (circulant). ka=2*v1+p, nu=u.
  for (int idx = tid; idx < 2 * r * r; idx += 256) {
    int ka = idx / r, u = idx - (idx / r) * r;
    int v1 = ka >> 1, p = ka & 1;
    int d = (u - v1 + r) % r;
    bput(b4h, b4l, 8, ka, u, p ? -zi[d] : zr[d]);
  }
}

// ---------------------------------------------------------------------------
// Per-wave MFMA tile helper. A (split-bf16) from LDS (row-major, aPad shorts),
// B (split-bf16) frag-swizzled from global. 3-term split product.
// ---------------------------------------------------------------------------
__device__ __forceinline__ void run_gemm_tile(
    const ushortt* aH, const ushortt* aL, int aPad, int aColBase,
    const ushortt* bH, const ushortt* bL, int NtA,
    int kt, int mts, int Mt, int nts, int Nt, int nt0,
    int mh, int nq, int lane, float4v acc[4][2]) {
  int q = lane >> 4, l16 = lane & 15;
  short8v afh[4], afl[4];
  int nm = 0;
  for (int im = 0; im < mts; im++) {
    int mt = mh * mts + im;
    if (mt >= Mt) break;
    int off = (mt * 16 + l16) * aPad + aColBase + q * 8;
    afh[im] = *(const short8v*)(aH + off);
    afl[im] = *(const short8v*)(aL + off);
    nm = im + 1;
  }
  for (int in_ = 0; in_ < nts; in_++) {
    int ntl = nq * nts + in_;
    if (ntl >= Nt) continue;
    size_t boff = (((size_t)(kt * NtA + nt0 + ntl)) * 64 + lane) * 8;
    short8v bh = *(const short8v*)(bH + boff);
    short8v bl = *(const short8v*)(bL + boff);
    for (int im = 0; im < nm; im++) {
      float4v t = acc[im][in_];
      t = __builtin_amdgcn_mfma_f32_16x16x32_bf16(afh[im], bh, t, 0, 0, 0);
      t = __builtin_amdgcn_mfma_f32_16x16x32_bf16(afl[im], bh, t, 0, 0, 0);
      t = __builtin_amdgcn_mfma_f32_16x16x32_bf16(afh[im], bl, t, 0, 0, 0);
      acc[im][in_] = t;
    }
  }
}

// ---------------------------------------------------------------------------
// Pipeline kernel: per (ch, res) block; MFMA GEMM stages + pool + ring.
// ---------------------------------------------------------------------------
__global__ __launch_bounds__(NTP, 2) void pipe_kernel(const float* __restrict__ x, int res_hi) {
  int rorder = blockIdx.x / NCH;
  int ch = blockIdx.x - rorder * NCH;
  int r = res_hi - 2 * rorder;
  const int tid = threadIdx.x;
  const int lane = tid & 63, wav = tid >> 6;
  const int mh = wav >> 2, nq = wav & 3;
  const int q = lane >> 4, l16 = lane & 15;

  int c = r >> 1, cp1 = c + 1, h = c >> 1, hp1 = h + 1;
  int ri = (r - 16) >> 1;
  int jp = ((cp1 + 15) >> 4) << 4;
  int K2p = 2 * jp;
  int K3p = ((r + 31) >> 5) << 5;
  int K4p = ((2 * r + 31) >> 5) << 5;
  int Mr = ((r + 15) >> 4) << 4;
  int IPAD = K3p + 8, UPAD = K4p + 8;
  int UC = (r > 96) ? 64 : 32;
  bool is128 = (r == 128);

  extern __shared__ char smem[];
  float* tw = (float*)smem;
  size_t off = (size_t)(((2 * r * 4) + 15) / 16) * 16;
  ushortt* ImgH = (ushortt*)(smem + off); off += (size_t)Mr * IPAD * 2;
  ushortt* ImgL = (ushortt*)(smem + off); off += (size_t)Mr * IPAD * 2;
  char* pbase = smem + off;
  // phase A overlay
  ushortt* AsH = (ushortt*)pbase;
  ushortt* AsL = (ushortt*)(pbase + 5120);
  float*   Tsyn = (float*)(pbase + 10240);
  // phase B overlay
  ushortt* UtH = (ushortt*)pbase;
  ushortt* UtL = (ushortt*)(pbase + (size_t)32 * UPAD * 2);
  float*   P   = (float*)(pbase + 2 * ((size_t)32 * UPAD * 2));
  // phase C overlay
  float2*  P1  = (float2*)pbase;

  for (int t = tid; t < r; t += NTP) {
    float s, co; sincosf(6.283185307179586f * (float)t / (float)r, &s, &co);
    tw[2 * t] = co; tw[2 * t + 1] = s;
  }

  const float2* Xc = g_X + (size_t)ch * (128 * 65);
  const ushortt* b1h = g_B1h + (size_t)ri * B1SLOT; const ushortt* b1l = g_B1l + (size_t)ri * B1SLOT;
  const ushortt* b2h = g_B2h + (size_t)ri * B2SLOT; const ushortt* b2l = g_B2l + (size_t)ri * B2SLOT;
  const ushortt* b3h = g_B3h + (size_t)ri * B3SLOT; const ushortt* b3l = g_B3l + (size_t)ri * B3SLOT;
  const ushortt* b4h = g_B4h + (size_t)ri * B4SLOT; const ushortt* b4l = g_B4l + (size_t)ri * B4SLOT;
  __syncthreads();

  // =================== PHASE A: T + synthesis + GELU -> IMG ===================
  if (!is128) {
    int Kt1 = K4p >> 5;                 // K1p == rnd32(2r) == K4p
    int Kt2 = K2p >> 5;
    for (int uc = 0; uc < r; uc += UC) {
      int un = min(UC, r - uc);
      for (int e = tid; e < UC * K2p; e += NTP) Tsyn[e] = 0.f;
      __syncthreads();
      // ---- stage T: out[j][2u+s'] over K=(s,k1) ----
      float4v acc[4][2];
      for (int i_ = 0; i_ < 4; i_++) for (int j_ = 0; j_ < 2; j_++) { float4v z = {0.f, 0.f, 0.f, 0.f}; acc[i_][j_] = z; }
      int Mt = (cp1 + 15) >> 4, mts = (Mt + 1) >> 1;
      int Nt = (2 * un + 15) >> 4, nts = (Nt + 3) >> 2;
      int nt0 = uc >> 3;
      for (int kt = 0; kt < Kt1; kt++) {
        for (int e = tid; e < 2048; e += NTP) {
          int row = e & 63, kl = e >> 6;         // row = j (coalesced over j)
          int kap = kt * 32 + kl;
          float v = 0.f;
          if (row < cp1 && kap < 2 * r) {
            int s = kap >= r;
            int k1 = kap - (s ? r : 0);
            int src = (k1 < c) ? k1 : (128 - r + k1);
            float2 e2 = Xc[src * 65 + row];
            v = s ? e2.y : e2.x;
          }
          bsplit(v, AsH[row * 40 + kl], AsL[row * 40 + kl]);
        }
        __syncthreads();
        run_gemm_tile(AsH, AsL, 40, 0, b1h, b1l, 16, kt, mts, Mt, nts, Nt, nt0, mh, nq, lane, acc);
        __syncthreads();
      }
      for (int im = 0; im < mts; im++) {
        int mt = mh * mts + im; if (mt >= Mt) break;
        for (int in_ = 0; in_ < nts; in_++) {
          int ntl = nq * nts + in_; if (ntl >= Nt) continue;
          int colb = (nt0 + ntl) * 16 + l16;
          if (colb >= 2 * r) continue;
          int u = colb >> 1, sp = colb & 1;
          for (int rg = 0; rg < 4; rg++) {
            int j = mt * 16 + q * 4 + rg;
            if (j < cp1) Tsyn[(u - uc) * K2p + sp * jp + j] = acc[im][in_][rg];
          }
        }
      }
      __syncthreads();
      // ---- synthesis: img[u][v] = gelu(Tsyn . CS) ----
      for (int i_ = 0; i_ < 4; i_++) for (int j_ = 0; j_ < 2; j_++) { float4v z = {0.f, 0.f, 0.f, 0.f}; acc[i_][j_] = z; }
      int MtS = (un + 15) >> 4, mtsS = (MtS + 1) >> 1;
      int NtS = (r + 15) >> 4, ntsS = (NtS + 3) >> 2;
      for (int kt = 0; kt < Kt2; kt++) {
        for (int e = tid; e < 2048; e += NTP) {
          int row = e >> 5, kl = e & 31;
          float v = (row < UC) ? Tsyn[row * K2p + kt * 32 + kl] : 0.f;
          bsplit(v, AsH[row * 40 + kl], AsL[row * 40 + kl]);
        }
        __syncthreads();
        run_gemm_tile(AsH, AsL, 40, 0, b2h, b2l, 8, kt, mtsS, MtS, ntsS, NtS, 0, mh, nq, lane, acc);
        __syncthreads();
      }
      for (int im = 0; im < mtsS; im++) {
        int mt = mh * mtsS + im; if (mt >= MtS) break;
        for (int in_ = 0; in_ < ntsS; in_++) {
          int ntl = nq * ntsS + in_; if (ntl >= NtS) continue;
          int v = ntl * 16 + l16;
          if (v >= r) continue;
          for (int rg = 0; rg < 4; rg++) {
            int ul = mt * 16 + q * 4 + rg;
            if (ul < un) {
              float g = gelu_exact(acc[im][in_][rg]);
              int ix = (uc + ul) * IPAD + v;
              bsplit(g, ImgH[ix], ImgL[ix]);
            }
          }
        }
      }
      __syncthreads();
    }
  } else {
    const float* xc = x + (size_t)ch * 128 * 128;
    for (int e = tid; e < 128 * 128; e += NTP) {
      int row = e >> 7, col = e & 127;
      float g = gelu_exact(xc[e]);
      bsplit(g, ImgH[row * IPAD + col], ImgL[row * IPAD + col]);
    }
    __syncthreads();
  }

  // zero IMG K-pad cols and UTc K-pad cols
  if (K3p > r) {
    int w = K3p - r;
    for (int e = tid; e < r * w; e += NTP) {
      int row = e / w, col = r + (e - row * w);
      ImgH[row * IPAD + col] = 0; ImgL[row * IPAD + col] = 0;
    }
  }
  if (K4p > 2 * r) {
    int w = K4p - 2 * r;
    for (int e = tid; e < 32 * w; e += NTP) {
      int row = e / w, col = 2 * r + (e - row * w);
      UtH[row * UPAD + col] = 0; UtL[row * UPAD + col] = 0;
    }
  }
  __syncthreads();

  // =================== PHASE B: smooth (s1, s2) + pool -> P (transposed) ======
  {
    int Kt3 = K3p >> 5, Kt4 = K4p >> 5;
    int Mt1 = (r + 15) >> 4, mts1 = (Mt1 + 1) >> 1;
    int Nt4 = (r + 15) >> 4, nts4 = (Nt4 + 3) >> 2;
    for (int v0 = 0; v0 < r; v0 += 32) {
      // s1: U[v1][2*v2'+p] slice for v2' in [v0, v0+32)
      float4v acc[4][2];
      for (int i_ = 0; i_ < 4; i_++) for (int j_ = 0; j_ < 2; j_++) { float4v z = {0.f, 0.f, 0.f, 0.f}; acc[i_][j_] = z; }
      int ncols = min(64, 2 * r - 2 * v0);
      int NtS1 = (ncols + 15) >> 4, ntsS1 = (NtS1 + 3) >> 2;
      for (int kt = 0; kt < Kt3; kt++)
        run_gemm_tile(ImgH, ImgL, IPAD, kt * 32, b3h, b3l, 16, kt, mts1, Mt1, ntsS1, NtS1, v0 >> 3, mh, nq, lane, acc);
      // epilogue -> UTc (bf16 split), free transpose
      for (int im = 0; im < mts1; im++) {
        int mt = mh * mts1 + im; if (mt >= Mt1) break;
        for (int in_ = 0; in_ < ntsS1; in_++) {
          int ntl = nq * ntsS1 + in_; if (ntl >= NtS1) continue;
          int nu = 2 * v0 + ntl * 16 + l16;
          int v2p = nu >> 1, p = nu & 1;
          if (v2p >= r) continue;
          for (int rg = 0; rg < 4; rg++) {
            int v1 = mt * 16 + q * 4 + rg;
            if (v1 < r) {
              int ix = (v2p - v0) * UPAD + 2 * v1 + p;
              bsplit(acc[im][in_][rg], UtH[ix], UtL[ix]);
            }
          }
        }
      }
      __syncthreads();
      // s2: outT[v2'][u] = UT . Z2 ; fused 2x2 maxpool into P
      float4v ac2[4][2];
      for (int i_ = 0; i_ < 4; i_++) for (int j_ = 0; j_ < 2; j_++) { float4v z = {0.f, 0.f, 0.f, 0.f}; ac2[i_][j_] = z; }
      for (int kt = 0; kt < Kt4; kt++)
        run_gemm_tile(UtH, UtL, UPAD, kt * 32, b4h, b4l, 8, kt, 1, 2, nts4, Nt4, 0, mh, nq, lane, ac2);
      for (int in_ = 0; in_ < nts4; in_++) {
        int ntl = nq * nts4 + in_; if (ntl >= Nt4) continue;
        int u = ntl * 16 + l16;
        float4v a = ac2[0][in_];
        float rp0 = fmaxf(a[0], a[1]);
        float rp1 = fmaxf(a[2], a[3]);
        float o0 = __shfl_xor(rp0, 1, 64);
        float o1 = __shfl_xor(rp1, 1, 64);
        if (!(lane & 1) && u < r) {
          int vb = v0 + mh * 16 + q * 4;
          if (vb < r)     P[(vb >> 1) * c + (u >> 1)] = fmaxf(rp0, o0);
          if (vb + 2 < r) P[((vb + 2) >> 1) * c + (u >> 1)] = fmaxf(rp1, o1);
        }
      }
      __syncthreads();
    }
  }

  // =================== PHASE C: ring DFT (P holds pooled transposed) =========
  for (int idx = tid; idx < c * hp1; idx += NTP) {
    int k2 = idx % hp1, i = idx / hp1;
    int dt = (2 * k2) % r;
    float cb = tw[2 * dt], sbr = tw[2 * dt + 1];
    int dt2 = (2 * dt) % r;
    float cs = tw[2 * dt2], ss = tw[2 * dt2 + 1];
    float ca = 1.f, sa = 0.f;
    float ar = 0.f, ai = 0.f;
    int jj = 0;
    for (; jj + 1 < c; jj += 2) {
      float p0 = P[jj * c + i], q0 = P[(jj + 1) * c + i];
      ar += p0 * ca; ai -= p0 * sa;
      ar += q0 * cb; ai -= q0 * sbr;
      ROT(ca, sa, cs, ss); ROT(cb, sbr, cs, ss);
    }
    if (jj < c) { float p0 = P[jj * c + i]; ar += p0 * ca; ai -= p0 * sa; }
    P1[idx] = make_float2(ar, ai);
  }
  __syncthreads();
  float invcc = 1.0f / ((float)c * (float)c);
  float2* ringp = g_ring + ((size_t)ch * 57 + (size_t)ri) * 132;
  auto ring_out = [&](int k1, int k2, int slot) {
    int dt = (2 * k1) % r;
    float cb = tw[2 * dt], sbr = tw[2 * dt + 1];
    int dt2 = (2 * dt) % r;
    float cs = tw[2 * dt2], ss = tw[2 * dt2 + 1];
    float ca = 1.f, sa = 0.f;
    float ar = 0.f, ai = 0.f;
    int i = 0;
    for (; i + 1 < c; i += 2) {
      float2 e = P1[i * hp1 + k2];
      ar += e.x * ca + e.y * sa; ai += e.y * ca - e.x * sa;
      float2 e2 = P1[(i + 1) * hp1 + k2];
      ar += e2.x * cb + e2.y * sbr; ai += e2.y * cb - e2.x * sbr;
      ROT(ca, sa, cs, ss); ROT(cb, sbr, cs, ss);
    }
    if (i < c) {
      float2 e = P1[i * hp1 + k2];
      ar += e.x * ca + e.y * sa; ai += e.y * ca - e.x * sa;
    }
    ringp[slot] = make_float2(ar * invcc, ai * invcc);
  };
  if (r == 16) {
    for (int idx = tid; idx < 40; idx += NTP) ring_out(idx / 5, idx % 5, idx);
  } else {
    int nA = hp1, total = 2 * nA + c;
    for (int idx = tid; idx < total; idx += NTP) {
      int k1, k2;
      if (idx < nA) { k1 = h; k2 = idx; }
      else if (idx < 2 * nA) { k1 = c - h; k2 = idx - nA; }
      else { k1 = idx - 2 * nA; k2 = h; }
      ring_out(k1, k2, idx);
    }
  }
}

// ---------------------------------------------------------------------------
// Final assembly (verified).
// ---------------------------------------------------------------------------
__device__ __forceinline__ float2 loadA(int ch, int k1, int k2) {
  int o = g_owner[k1 * 33 + k2];
  if (o < 0) return make_float2(0.f, 0.f);
  return g_ring[((size_t)ch * 57 + (o >> 8)) * 132 + (o & 255)];
}

__global__ __launch_bounds__(NT) void assemble_kernel(float* __restrict__ out) {
  size_t gid = (size_t)blockIdx.x * NT + threadIdx.x;
  if (gid >= (size_t)NCH * 4096) return;
  int ch = (int)(gid >> 12);
  int rem = (int)(gid & 4095);
  int k1 = rem >> 6, k2f = rem & 63;
  float2 v;
  if (k2f <= 32) {
    float2 a = loadA(ch, k1, k2f);
    if (k2f == 0 || k2f == 32) {
      float2 b = loadA(ch, (64 - k1) & 63, k2f);
      v = make_float2(0.5f * (a.x + b.x), 0.5f * (a.y - b.y));
    } else v = a;
  } else {
    float2 a = loadA(ch, (64 - k1) & 63, 64 - k2f);
    v = make_float2(a.x, -a.y);
  }
  out[2 * gid] = v.x;
  out[2 * gid + 1] = v.y;
}

// ---------------------------------------------------------------------------
static size_t lds_bytes(int r) {
  int c = r >> 1, cp1 = c + 1;
  int jp = ((cp1 + 15) >> 4) << 4;
  int K2p = 2 * jp;
  int K3p = ((r + 31) >> 5) << 5;
  int K4p = ((2 * r + 31) >> 5) << 5;
  int Mr = ((r + 15) >> 4) << 4;
  int IPAD = K3p + 8, UPAD = K4p + 8;
  int UC = (r > 96) ? 64 : 32;
  size_t tw = (size_t)(((2 * r * 4) + 15) / 16) * 16;
  size_t img = (size_t)2 * Mr * IPAD * 2;
  size_t pa = 10240 + (size_t)UC * K2p * 4;
  size_t pb = 2 * ((size_t)32 * UPAD * 2) + (size_t)c * c * 4;
  size_t un = pa > pb ? pa : pb;
  return tw + img + un;
}

extern "C" void kernel_launch(void* const* d_in, const int* in_sizes, int n_in,
                              void* d_out, int out_size, void* d_ws, size_t ws_size,
                              hipStream_t stream) {
  (void)in_sizes; (void)n_in; (void)d_ws; (void)ws_size; (void)out_size;
  const float* x = (const float*)d_in[0];
  float* out = (float*)d_out;

  hipFuncSetAttribute(reinterpret_cast<const void*>(pipe_kernel),
                      hipFuncAttributeMaxDynamicSharedMemorySize, 160 * 1024);

  hipLaunchKernelGGL(owner_kernel, dim3(9), dim3(NT), 0, stream);
  hipLaunchKernelGGL(basis_kernel, dim3(57), dim3(256), 0, stream);
  hipLaunchKernelGGL(r1_kernel, dim3(NCH * 8), dim3(NT), 0, stream, x);
  hipLaunchKernelGGL(r2_kernel, dim3(NCH * 9), dim3(NT), 0, stream);

  hipLaunchKernelGGL(pipe_kernel, dim3(15 * NCH), dim3(NTP), lds_bytes(126), stream, x, 126); // 98..126
  hipLaunchKernelGGL(pipe_kernel, dim3(1 * NCH),  dim3(NTP), lds_bytes(128), stream, x, 128); // 128
  hipLaunchKernelGGL(pipe_kernel, dim3(16 * NCH), dim3(NTP), lds_bytes(96),  stream, x, 96);  // 66..96
  hipLaunchKernelGGL(pipe_kernel, dim3(16 * NCH), dim3(NTP), lds_bytes(64),  stream, x, 64);  // 34..64
  hipLaunchKernelGGL(pipe_kernel, dim3(9 * NCH),  dim3(NTP), lds_bytes(32),  stream, x, 32);  // 16..32

  hipLaunchKernelGGL(assemble_kernel, dim3((NCH * 4096) / NT), dim3(NT), 0, stream, out);
}